// Round 1
// baseline (1516.252 us; speedup 1.0000x reference)
//
#include <hip/hip_runtime.h>
#include <math.h>

#define BB 4
#define TT 2048
#define NH 8
#define HD 64     // head dim
#define EMB 512   // N*C = HEADS*HEAD_DIM

// ---------------------------------------------------------------------------
// Kernel 1: Q projection. q[m, o] = sum_i queries[m, i] * Wq[o, i]
// A: [8192, 512], W: [512, 512] (row o, col i), Q: [8192, 512]
// 64x64 output tile per block, 4x4 micro-tile per thread, K-tile = 16.
// ---------------------------------------------------------------------------
__global__ __launch_bounds__(256) void qproj_kernel(const float* __restrict__ A,
                                                    const float* __restrict__ W,
                                                    float* __restrict__ Q) {
    __shared__ float As[16][68];   // [k][m], pad to 68 for bank spread
    __shared__ float Ws[16][68];   // [k][o]
    const int tid = threadIdx.x;
    const int bm = blockIdx.x * 64;
    const int bo = blockIdx.y * 64;
    const int tx = tid & 15, ty = tid >> 4;
    const int lm = tid >> 2;         // 0..63
    const int lk = (tid & 3) * 4;    // 0,4,8,12
    float acc[4][4] = {};
    for (int k0 = 0; k0 < EMB; k0 += 16) {
        float4 a4 = *(const float4*)(A + (size_t)(bm + lm) * EMB + k0 + lk);
        float4 w4 = *(const float4*)(W + (size_t)(bo + lm) * EMB + k0 + lk);
        As[lk+0][lm]=a4.x; As[lk+1][lm]=a4.y; As[lk+2][lm]=a4.z; As[lk+3][lm]=a4.w;
        Ws[lk+0][lm]=w4.x; Ws[lk+1][lm]=w4.y; Ws[lk+2][lm]=w4.z; Ws[lk+3][lm]=w4.w;
        __syncthreads();
        #pragma unroll
        for (int k = 0; k < 16; k++) {
            float a[4], w[4];
            #pragma unroll
            for (int i = 0; i < 4; i++) a[i] = As[k][ty*4+i];
            #pragma unroll
            for (int j = 0; j < 4; j++) w[j] = Ws[k][tx*4+j];
            #pragma unroll
            for (int i = 0; i < 4; i++)
                #pragma unroll
                for (int j = 0; j < 4; j++) acc[i][j] = fmaf(a[i], w[j], acc[i][j]);
        }
        __syncthreads();
    }
    #pragma unroll
    for (int i = 0; i < 4; i++)
        #pragma unroll
        for (int j = 0; j < 4; j++)
            Q[(size_t)(bm + ty*4 + i) * EMB + bo + tx*4 + j] = acc[i][j];
}

// ---------------------------------------------------------------------------
// Kernel 2: flash attention + fused FC epilogue.
// Block = 256 threads (4 waves). Each wave owns 8 query rows (lane = dim d
// for q/acc, lane = key j during energy). K/V staged in 64-key LDS tiles.
// ---------------------------------------------------------------------------
#define RPW 8                 // rows per wave
#define ROWS 32               // rows per block
#define KTILE 64

__device__ __forceinline__ float rdlane(float v, int l) {
    return __uint_as_float(__builtin_amdgcn_readlane(__float_as_uint(v), l));
}

__global__ __launch_bounds__(256) void attn_kernel(const float* __restrict__ qws,
                                                   const float* __restrict__ keys,
                                                   const float* __restrict__ values,
                                                   const float* __restrict__ Wfc,
                                                   const float* __restrict__ bfc,
                                                   float* __restrict__ out) {
    __shared__ float Kt[KTILE][65];
    __shared__ float Vt[KTILE][65];
    __shared__ float Wfs[64][64];   // Wfs[d][e] = Wfc[e*64 + d]
    __shared__ float bfs[64];

    const int tid  = threadIdx.x;
    const int lane = tid & 63;
    const int wave = tid >> 6;
    const int h = blockIdx.y;
    const int b = blockIdx.z;
    const int rowBase = blockIdx.x * ROWS + wave * RPW;

    // Stage W_fc (transposed) and bias.
    #pragma unroll
    for (int rep = 0; rep < 4; rep++) {
        int e4 = rep * 256 + tid;      // 1024 float4 units over 4096 elems
        int e = e4 >> 4;               // 0..63
        int d = (e4 & 15) * 4;
        float4 w4 = *(const float4*)(Wfc + e * 64 + d);
        Wfs[d+0][e] = w4.x; Wfs[d+1][e] = w4.y; Wfs[d+2][e] = w4.z; Wfs[d+3][e] = w4.w;
    }
    if (tid < 64) bfs[tid] = bfc[tid];

    // Load q rows: qreg[r] holds q[row_r][d = lane].
    float qreg[RPW];
    #pragma unroll
    for (int r = 0; r < RPW; r++)
        qreg[r] = qws[(((size_t)b * TT + rowBase + r) * NH + h) * HD + lane];

    float m[RPW], lsum[RPW], acc[RPW];
    #pragma unroll
    for (int r = 0; r < RPW; r++) { m[r] = -INFINITY; lsum[r] = 0.f; acc[r] = 0.f; }

    const float* kbase = keys   + ((size_t)b * TT * NH + h) * HD;
    const float* vbase = values + ((size_t)b * TT * NH + h) * HD;

    for (int kt0 = 0; kt0 < TT; kt0 += KTILE) {
        __syncthreads();   // previous tile fully consumed (also covers Wfs init)
        #pragma unroll
        for (int rep = 0; rep < 4; rep++) {
            int e4 = rep * 256 + tid;
            int kr = e4 >> 4;            // 0..63 key within tile
            int d  = (e4 & 15) * 4;
            size_t g = ((size_t)(kt0 + kr) * NH) * HD + d;
            float4 k4 = *(const float4*)(kbase + g);
            float4 v4 = *(const float4*)(vbase + g);
            Kt[kr][d+0]=k4.x; Kt[kr][d+1]=k4.y; Kt[kr][d+2]=k4.z; Kt[kr][d+3]=k4.w;
            Vt[kr][d+0]=v4.x; Vt[kr][d+1]=v4.y; Vt[kr][d+2]=v4.z; Vt[kr][d+3]=v4.w;
        }
        __syncthreads();

        // Energy: lane = key j. en[r] = sum_d q[r][d] * K[j][d]
        float en[RPW];
        #pragma unroll
        for (int r = 0; r < RPW; r++) en[r] = 0.f;
        #pragma unroll 16
        for (int d = 0; d < 64; d++) {
            float kv = Kt[lane][d];       // bank (lane+d)%32: 2-way, free
            #pragma unroll
            for (int r = 0; r < RPW; r++)
                en[r] = fmaf(rdlane(qreg[r], d), kv, en[r]);
        }

        // Mask (-1e9 pre-scale, as in reference) + scale + online softmax.
        const int key = kt0 + lane;
        float p[RPW], alph[RPW];
        #pragma unroll
        for (int r = 0; r < RPW; r++) {
            float e = en[r];
            if (key == rowBase + r) e = -1e9f;
            e *= 0.125f;                  // 1/sqrt(64)
            float tm = e;
            #pragma unroll
            for (int s = 32; s > 0; s >>= 1)
                tm = fmaxf(tm, __shfl_xor(tm, s, 64));
            float mn = fmaxf(m[r], tm);
            float pv = __expf(e - mn);
            float ps = pv;
            #pragma unroll
            for (int s = 32; s > 0; s >>= 1)
                ps += __shfl_xor(ps, s, 64);
            alph[r] = __expf(m[r] - mn);  // exp(-inf)=0 handles first tile
            m[r] = mn;
            lsum[r] = lsum[r] * alph[r] + ps;
            p[r] = pv;
        }

        // PV: lane = dim d. acc[r][d] = acc*alpha + sum_j p[r][j] * V[j][d]
        #pragma unroll
        for (int r = 0; r < RPW; r++) acc[r] *= alph[r];
        #pragma unroll 16
        for (int j = 0; j < 64; j++) {
            float vv = Vt[j][lane];       // stride-1: conflict-free
            #pragma unroll
            for (int r = 0; r < RPW; r++)
                acc[r] = fmaf(rdlane(p[r], j), vv, acc[r]);
        }
    }

    // Epilogue: normalize + FC (out_e = sum_d a_d * Wfc[e][d] + b_e)
    #pragma unroll
    for (int r = 0; r < RPW; r++) {
        float a = acc[r] / lsum[r];
        float o = bfs[lane];
        #pragma unroll 16
        for (int d = 0; d < 64; d++)
            o = fmaf(rdlane(a, d), Wfs[d][lane], o);
        out[(((size_t)b * TT + rowBase + r) * NH + h) * HD + lane] = o;
    }
}

// ---------------------------------------------------------------------------
extern "C" void kernel_launch(void* const* d_in, const int* in_sizes, int n_in,
                              void* d_out, int out_size, void* d_ws, size_t ws_size,
                              hipStream_t stream) {
    const float* values  = (const float*)d_in[0];
    const float* keys    = (const float*)d_in[1];
    const float* queries = (const float*)d_in[2];
    const float* Wq      = (const float*)d_in[3];
    const float* Wfc     = (const float*)d_in[4];
    const float* bfc     = (const float*)d_in[5];
    float* out = (float*)d_out;
    float* qws = (float*)d_ws;   // needs 8192*512*4 = 16.78 MB

    qproj_kernel<<<dim3((BB*TT)/64, EMB/64), 256, 0, stream>>>(queries, Wq, qws);
    attn_kernel<<<dim3(TT/ROWS, NH, BB), 256, 0, stream>>>(qws, keys, values, Wfc, bfc, out);
}

// Round 2
// 345.225 us; speedup vs baseline: 4.3921x; 4.3921x over previous
//
#include <hip/hip_runtime.h>
#include <math.h>

#define BB 4
#define TT 2048
#define NH 8
#define HD 64
#define EMB 512
#define PITCH 88   // bf16 elems per LDS row: 176 B, 16B-aligned, 2-way banks (free)

typedef unsigned short u16;
typedef short short8 __attribute__((ext_vector_type(8)));
typedef float f32x4 __attribute__((ext_vector_type(4)));

#define MFMA(a, b, c) __builtin_amdgcn_mfma_f32_16x16x32_bf16((a), (b), (c), 0, 0, 0)

// split helpers: hi = truncated-top-16 bf16, lo = bf16(a - hi). 3-term product
// err ~2^-15 rel -- effectively fp32 through the MFMA pipe.
__device__ __forceinline__ float hi_part(float a) {
    return __uint_as_float(__float_as_uint(a) & 0xffff0000u);
}
__device__ __forceinline__ unsigned pack_hi2(float a, float b) {
    return (__float_as_uint(a) >> 16) | (__float_as_uint(b) & 0xffff0000u);
}

// ---------------------------------------------------------------------------
// Kernel 1: Q projection GEMM (fp32 compute), emits split bf16 Qh/Ql.
// ---------------------------------------------------------------------------
__global__ __launch_bounds__(256) void qproj_split(const float* __restrict__ A,
                                                   const float* __restrict__ W,
                                                   u16* __restrict__ Qh,
                                                   u16* __restrict__ Ql) {
    __shared__ float As[16][68];
    __shared__ float Ws[16][68];
    const int tid = threadIdx.x;
    const int bm = blockIdx.x * 64;
    const int bo = blockIdx.y * 64;
    const int tx = tid & 15, ty = tid >> 4;
    const int lm = tid >> 2;
    const int lk = (tid & 3) * 4;
    float acc[4][4] = {};
    for (int k0 = 0; k0 < EMB; k0 += 16) {
        float4 a4 = *(const float4*)(A + (size_t)(bm + lm) * EMB + k0 + lk);
        float4 w4 = *(const float4*)(W + (size_t)(bo + lm) * EMB + k0 + lk);
        As[lk+0][lm]=a4.x; As[lk+1][lm]=a4.y; As[lk+2][lm]=a4.z; As[lk+3][lm]=a4.w;
        Ws[lk+0][lm]=w4.x; Ws[lk+1][lm]=w4.y; Ws[lk+2][lm]=w4.z; Ws[lk+3][lm]=w4.w;
        __syncthreads();
        #pragma unroll
        for (int k = 0; k < 16; k++) {
            float a[4], w[4];
            #pragma unroll
            for (int i = 0; i < 4; i++) a[i] = As[k][ty*4+i];
            #pragma unroll
            for (int j = 0; j < 4; j++) w[j] = Ws[k][tx*4+j];
            #pragma unroll
            for (int i = 0; i < 4; i++)
                #pragma unroll
                for (int j = 0; j < 4; j++) acc[i][j] = fmaf(a[i], w[j], acc[i][j]);
        }
        __syncthreads();
    }
    #pragma unroll
    for (int i = 0; i < 4; i++) {
        size_t o = (size_t)(bm + ty*4 + i) * EMB + bo + tx*4;
        float p0=acc[i][0], p1=acc[i][1], p2=acc[i][2], p3=acc[i][3];
        uint2 hh = make_uint2(pack_hi2(p0,p1), pack_hi2(p2,p3));
        float l0=p0-hi_part(p0), l1=p1-hi_part(p1), l2=p2-hi_part(p2), l3=p3-hi_part(p3);
        uint2 ll = make_uint2(pack_hi2(l0,l1), pack_hi2(l2,l3));
        *(uint2*)(Qh + o) = hh;
        *(uint2*)(Ql + o) = ll;
    }
}

// ---------------------------------------------------------------------------
// Kernel 2: convert K -> [b,h,t,d] hi/lo, V -> transposed [b,h,d,t] hi/lo,
// Wfc -> hi/lo (block 0 only).
// ---------------------------------------------------------------------------
__global__ __launch_bounds__(256) void convert_kv(const float* __restrict__ K,
                                                  const float* __restrict__ V,
                                                  const float* __restrict__ Wfc,
                                                  u16* __restrict__ Kh, u16* __restrict__ Kl,
                                                  u16* __restrict__ Vth, u16* __restrict__ Vtl,
                                                  u16* __restrict__ Wh, u16* __restrict__ Wl) {
    __shared__ float Vf[64][68];
    const int tid = threadIdx.x;
    const int kt0 = blockIdx.x * 64, h = blockIdx.y, b = blockIdx.z;
    const int t = tid >> 2, c0 = (tid & 3) * 16;

    // K: regroup [b,t,h*64+d] -> [b,h,t,d], split.
    {
        const float* kp = K + ((size_t)(b*TT + kt0 + t)) * EMB + h*HD + c0;
        float v[16];
        #pragma unroll
        for (int j = 0; j < 4; j++) {
            float4 f = *(const float4*)(kp + 4*j);
            v[4*j]=f.x; v[4*j+1]=f.y; v[4*j+2]=f.z; v[4*j+3]=f.w;
        }
        unsigned hh[8], ll[8];
        #pragma unroll
        for (int j = 0; j < 8; j++) {
            hh[j] = pack_hi2(v[2*j], v[2*j+1]);
            ll[j] = pack_hi2(v[2*j]-hi_part(v[2*j]), v[2*j+1]-hi_part(v[2*j+1]));
        }
        u16* kd = Kh + ((size_t)(b*NH + h)*TT + kt0 + t)*HD + c0;
        u16* kl = Kl + ((size_t)(b*NH + h)*TT + kt0 + t)*HD + c0;
        *(uint4*)kd = make_uint4(hh[0],hh[1],hh[2],hh[3]);
        *(uint4*)(kd+8) = make_uint4(hh[4],hh[5],hh[6],hh[7]);
        *(uint4*)kl = make_uint4(ll[0],ll[1],ll[2],ll[3]);
        *(uint4*)(kl+8) = make_uint4(ll[4],ll[5],ll[6],ll[7]);
    }
    // V: load [t][d] tile, transpose via LDS, emit [b,h,d,t0..], split.
    {
        const float* vp = V + ((size_t)(b*TT + kt0 + t)) * EMB + h*HD + c0;
        #pragma unroll
        for (int j = 0; j < 4; j++)
            *(float4*)&Vf[t][c0 + 4*j] = *(const float4*)(vp + 4*j);
    }
    __syncthreads();
    {
        const int d = tid >> 2, t0 = (tid & 3) * 16;
        float v[16];
        #pragma unroll
        for (int i = 0; i < 16; i++) v[i] = Vf[t0 + i][d];
        unsigned hh[8], ll[8];
        #pragma unroll
        for (int j = 0; j < 8; j++) {
            hh[j] = pack_hi2(v[2*j], v[2*j+1]);
            ll[j] = pack_hi2(v[2*j]-hi_part(v[2*j]), v[2*j+1]-hi_part(v[2*j+1]));
        }
        u16* vd = Vth + ((size_t)(b*NH + h)*HD + d)*TT + kt0 + t0;
        u16* vl = Vtl + ((size_t)(b*NH + h)*HD + d)*TT + kt0 + t0;
        *(uint4*)vd = make_uint4(hh[0],hh[1],hh[2],hh[3]);
        *(uint4*)(vd+8) = make_uint4(hh[4],hh[5],hh[6],hh[7]);
        *(uint4*)vl = make_uint4(ll[0],ll[1],ll[2],ll[3]);
        *(uint4*)(vl+8) = make_uint4(ll[4],ll[5],ll[6],ll[7]);
    }
    // Wfc split (one block).
    if (kt0 == 0 && h == 0 && b == 0) {
        const int i0 = tid * 16;
        float v[16];
        #pragma unroll
        for (int j = 0; j < 4; j++) {
            float4 f = *(const float4*)(Wfc + i0 + 4*j);
            v[4*j]=f.x; v[4*j+1]=f.y; v[4*j+2]=f.z; v[4*j+3]=f.w;
        }
        unsigned hh[8], ll[8];
        #pragma unroll
        for (int j = 0; j < 8; j++) {
            hh[j] = pack_hi2(v[2*j], v[2*j+1]);
            ll[j] = pack_hi2(v[2*j]-hi_part(v[2*j]), v[2*j+1]-hi_part(v[2*j+1]));
        }
        *(uint4*)(Wh + i0)     = make_uint4(hh[0],hh[1],hh[2],hh[3]);
        *(uint4*)(Wh + i0 + 8) = make_uint4(hh[4],hh[5],hh[6],hh[7]);
        *(uint4*)(Wl + i0)     = make_uint4(ll[0],ll[1],ll[2],ll[3]);
        *(uint4*)(Wl + i0 + 8) = make_uint4(ll[4],ll[5],ll[6],ll[7]);
    }
}

// ---------------------------------------------------------------------------
// Kernel 3: MFMA flash attention + fused FC.
// Block = 256 thr (4 waves), 64 q-rows per block, one (b,h).
// QK^T computed TRANSPOSED (D[key][q]) so softmax state is per-lane scalar
// and P writes to LDS are b64-contiguous.
// ---------------------------------------------------------------------------
__global__ __launch_bounds__(256) void attn_mfma(
        const u16* __restrict__ Qh, const u16* __restrict__ Ql,
        const u16* __restrict__ Kh, const u16* __restrict__ Kl,
        const u16* __restrict__ Vth, const u16* __restrict__ Vtl,
        const u16* __restrict__ Wh, const u16* __restrict__ Wl,
        const float* __restrict__ bfc, float* __restrict__ out) {
    __shared__ __align__(16) u16 smem[6 * 64 * PITCH];   // 67.6 KB -> 2 blocks/CU
    u16* KsH = smem;
    u16* KsL = smem + 1*64*PITCH;
    u16* VsH = smem + 2*64*PITCH;
    u16* VsL = smem + 3*64*PITCH;
    u16* PsH = smem + 4*64*PITCH;
    u16* PsL = smem + 5*64*PITCH;

    const int tid = threadIdx.x, lane = tid & 63, w = tid >> 6;
    const int quad = lane >> 4, l15 = lane & 15;
    const int qb = blockIdx.x * 64, h = blockIdx.y, b = blockIdx.z;

    // Preload Q B-frags: B[k=d][n=q], lane holds q=l15, d=quad*8+j (+kc*32).
    const size_t qoff = ((size_t)(b*TT + qb + w*16 + l15)) * EMB + h*HD + quad*8;
    short8 qf[2][2];
    qf[0][0] = *(const short8*)(Qh + qoff);
    qf[1][0] = *(const short8*)(Qh + qoff + 32);
    qf[0][1] = *(const short8*)(Ql + qoff);
    qf[1][1] = *(const short8*)(Ql + qoff + 32);

    const u16* kbH = Kh  + ((size_t)(b*NH + h)*TT)*HD;
    const u16* kbL = Kl  + ((size_t)(b*NH + h)*TT)*HD;
    const u16* vbH = Vth + ((size_t)(b*NH + h)*HD)*TT;
    const u16* vbL = Vtl + ((size_t)(b*NH + h)*HD)*TT;

    f32x4 co[4];
    #pragma unroll
    for (int m = 0; m < 4; m++) co[m] = (f32x4){0.f,0.f,0.f,0.f};
    float mprev = -INFINITY, lsum = 0.f;
    const int qg = qb + w*16 + l15;
    const int prow = (w*16 + l15) * PITCH;

    for (int kt0 = 0; kt0 < TT; kt0 += 64) {
        __syncthreads();
        // Stage K hi/lo ([t][d]) and V hi/lo ([d][t]) into pitch-88 LDS.
        #pragma unroll
        for (int i = 0; i < 2; i++) {
            const int ch = tid + i*256;          // 0..511
            const int r = ch >> 3, c = (ch & 7) * 8;   // row, u16 col
            uint4 a = *(const uint4*)(kbH + (size_t)(kt0 + r)*HD + c);
            uint4 d = *(const uint4*)(kbL + (size_t)(kt0 + r)*HD + c);
            uint4 e = *(const uint4*)(vbH + (size_t)r*TT + kt0 + c);
            uint4 f = *(const uint4*)(vbL + (size_t)r*TT + kt0 + c);
            *(uint4*)(KsH + r*PITCH + c) = a;
            *(uint4*)(KsL + r*PITCH + c) = d;
            *(uint4*)(VsH + r*PITCH + c) = e;
            *(uint4*)(VsL + r*PITCH + c) = f;
        }
        __syncthreads();

        // QK^T transposed: D[key][q]. A = K (m=key), B = Q.
        f32x4 sc[4];
        #pragma unroll
        for (int m = 0; m < 4; m++) {
            f32x4 c = (f32x4){0.f,0.f,0.f,0.f};
            #pragma unroll
            for (int kc = 0; kc < 2; kc++) {
                const int o = (m*16 + l15)*PITCH + kc*32 + quad*8;
                short8 ah = *(short8*)(KsH + o);
                short8 al = *(short8*)(KsL + o);
                c = MFMA(ah, qf[kc][0], c);
                c = MFMA(ah, qf[kc][1], c);
                c = MFMA(al, qf[kc][0], c);
            }
            sc[m] = c;
        }

        // Online softmax. Lane owns q=qg; its 16 scores are keys
        // kt0 + m*16 + quad*4 + r. Cross-quad reduce = shfl_xor 16,32.
        float pv[16];
        float tmax = -INFINITY;
        #pragma unroll
        for (int m = 0; m < 4; m++)
            #pragma unroll
            for (int r = 0; r < 4; r++) {
                float e = sc[m][r];
                const int kg = kt0 + m*16 + quad*4 + r;
                e = (kg == qg) ? -1e9f : e;   // mask BEFORE scale, as reference
                e *= 0.125f;
                pv[m*4 + r] = e;
                tmax = fmaxf(tmax, e);
            }
        tmax = fmaxf(tmax, __shfl_xor(tmax, 16, 64));
        tmax = fmaxf(tmax, __shfl_xor(tmax, 32, 64));
        const float mn = fmaxf(mprev, tmax);
        float psum = 0.f;
        #pragma unroll
        for (int i = 0; i < 16; i++) {
            float p = __expf(pv[i] - mn);
            pv[i] = p;
            psum += p;
        }
        psum += __shfl_xor(psum, 16, 64);
        psum += __shfl_xor(psum, 32, 64);
        const float alpha = __expf(mprev - mn);   // exp(-inf)=0 on first tile
        mprev = mn;
        lsum = lsum * alpha + psum;
        #pragma unroll
        for (int m = 0; m < 4; m++) {
            co[m][0] *= alpha; co[m][1] *= alpha;
            co[m][2] *= alpha; co[m][3] *= alpha;
        }

        // Write P split to LDS rows [q][key] (b64: 4 consecutive keys).
        #pragma unroll
        for (int m = 0; m < 4; m++) {
            float p0=pv[m*4], p1=pv[m*4+1], p2=pv[m*4+2], p3=pv[m*4+3];
            uint2 hh = make_uint2(pack_hi2(p0,p1), pack_hi2(p2,p3));
            float l0=p0-hi_part(p0), l1=p1-hi_part(p1), l2=p2-hi_part(p2), l3=p3-hi_part(p3);
            uint2 ll = make_uint2(pack_hi2(l0,l1), pack_hi2(l2,l3));
            const int off = prow + m*16 + quad*4;
            *(uint2*)(PsH + off) = hh;
            *(uint2*)(PsL + off) = ll;
        }

        // PV transposed: D[vdim][q]. A = V^T (Vs[d][t]), B = P^T (Ps[q][k]).
        // Within-wave DS ordering makes the P write->read safe without barrier.
        #pragma unroll
        for (int kc = 0; kc < 2; kc++) {
            const int po = prow + kc*32 + quad*8;
            short8 ph = *(short8*)(PsH + po);
            short8 pl = *(short8*)(PsL + po);
            #pragma unroll
            for (int m = 0; m < 4; m++) {
                const int vo = (m*16 + l15)*PITCH + kc*32 + quad*8;
                short8 vh = *(short8*)(VsH + vo);
                short8 vl = *(short8*)(VsL + vo);
                co[m] = MFMA(vh, ph, co[m]);
                co[m] = MFMA(vh, pl, co[m]);
                co[m] = MFMA(vl, ph, co[m]);
            }
        }
    }

    // Epilogue: normalize, FC via MFMA (D[e][q]), bias, transpose, store.
    const float rl = 1.0f / lsum;
    #pragma unroll
    for (int m = 0; m < 4; m++) {
        float a0=co[m][0]*rl, a1=co[m][1]*rl, a2=co[m][2]*rl, a3=co[m][3]*rl;
        uint2 hh = make_uint2(pack_hi2(a0,a1), pack_hi2(a2,a3));
        float l0=a0-hi_part(a0), l1=a1-hi_part(a1), l2=a2-hi_part(a2), l3=a3-hi_part(a3);
        uint2 ll = make_uint2(pack_hi2(l0,l1), pack_hi2(l2,l3));
        const int off = prow + m*16 + quad*4;
        *(uint2*)(PsH + off) = hh;
        *(uint2*)(PsL + off) = ll;
    }
    f32x4 cf[4];
    #pragma unroll
    for (int m = 0; m < 4; m++) cf[m] = (f32x4){0.f,0.f,0.f,0.f};
    #pragma unroll
    for (int kc = 0; kc < 2; kc++) {
        const int po = prow + kc*32 + quad*8;
        short8 bh = *(short8*)(PsH + po);
        short8 bl = *(short8*)(PsL + po);
        #pragma unroll
        for (int m = 0; m < 4; m++) {
            const int wo = (m*16 + l15)*HD + kc*32 + quad*8;
            short8 wh = *(const short8*)(Wh + wo);
            short8 wl = *(const short8*)(Wl + wo);
            cf[m] = MFMA(wh, bh, cf[m]);
            cf[m] = MFMA(wh, bl, cf[m]);
            cf[m] = MFMA(wl, bh, cf[m]);
        }
    }
    __syncthreads();   // all waves done with Ks reads before LDS reuse
    float* Ls = (float*)smem;   // 4 waves x 16 x 68 f32 (17.4 KB, fits in Ks)
    #pragma unroll
    for (int m = 0; m < 4; m++)
        *(f32x4*)(Ls + (w*16 + l15)*68 + m*16 + quad*4) = cf[m];
    // Per-wave region, within-wave write->read: no barrier needed.
    const int qr = lane >> 2, e0 = (lane & 3) * 16;
    const float* lrow = Ls + (w*16 + qr)*68 + e0;
    float* orow = out + ((size_t)((b*TT + qb + w*16 + qr)*NH + h))*HD + e0;
    #pragma unroll
    for (int j = 0; j < 4; j++) {
        f32x4 v = *(const f32x4*)(lrow + 4*j);
        float4 bv = *(const float4*)(bfc + e0 + 4*j);
        float4 o = make_float4(v[0]+bv.x, v[1]+bv.y, v[2]+bv.z, v[3]+bv.w);
        *(float4*)(orow + 4*j) = o;
    }
}

// ---------------------------------------------------------------------------
// Fallback path (round-1 kernels) if ws is too small for the split arrays.
// ---------------------------------------------------------------------------
__global__ __launch_bounds__(256) void qproj_f32(const float* __restrict__ A,
                                                 const float* __restrict__ W,
                                                 float* __restrict__ Q) {
    __shared__ float As[16][68];
    __shared__ float Ws[16][68];
    const int tid = threadIdx.x;
    const int bm = blockIdx.x * 64, bo = blockIdx.y * 64;
    const int tx = tid & 15, ty = tid >> 4;
    const int lm = tid >> 2, lk = (tid & 3) * 4;
    float acc[4][4] = {};
    for (int k0 = 0; k0 < EMB; k0 += 16) {
        float4 a4 = *(const float4*)(A + (size_t)(bm + lm) * EMB + k0 + lk);
        float4 w4 = *(const float4*)(W + (size_t)(bo + lm) * EMB + k0 + lk);
        As[lk+0][lm]=a4.x; As[lk+1][lm]=a4.y; As[lk+2][lm]=a4.z; As[lk+3][lm]=a4.w;
        Ws[lk+0][lm]=w4.x; Ws[lk+1][lm]=w4.y; Ws[lk+2][lm]=w4.z; Ws[lk+3][lm]=w4.w;
        __syncthreads();
        #pragma unroll
        for (int k = 0; k < 16; k++) {
            float a[4], w[4];
            #pragma unroll
            for (int i = 0; i < 4; i++) a[i] = As[k][ty*4+i];
            #pragma unroll
            for (int j = 0; j < 4; j++) w[j] = Ws[k][tx*4+j];
            #pragma unroll
            for (int i = 0; i < 4; i++)
                #pragma unroll
                for (int j = 0; j < 4; j++) acc[i][j] = fmaf(a[i], w[j], acc[i][j]);
        }
        __syncthreads();
    }
    #pragma unroll
    for (int i = 0; i < 4; i++)
        #pragma unroll
        for (int j = 0; j < 4; j++)
            Q[(size_t)(bm + ty*4 + i) * EMB + bo + tx*4 + j] = acc[i][j];
}

__device__ __forceinline__ float rdlane(float v, int l) {
    return __uint_as_float(__builtin_amdgcn_readlane(__float_as_uint(v), l));
}

__global__ __launch_bounds__(256) void attn_valu(const float* __restrict__ qws,
                                                 const float* __restrict__ keys,
                                                 const float* __restrict__ values,
                                                 const float* __restrict__ Wfc,
                                                 const float* __restrict__ bfc,
                                                 float* __restrict__ out) {
    __shared__ float Kt[64][65];
    __shared__ float Vt[64][65];
    __shared__ float Wfs[64][64];
    __shared__ float bfs[64];
    const int tid = threadIdx.x, lane = tid & 63, wave = tid >> 6;
    const int h = blockIdx.y, b = blockIdx.z;
    const int rowBase = blockIdx.x * 32 + wave * 8;
    #pragma unroll
    for (int rep = 0; rep < 4; rep++) {
        int e4 = rep * 256 + tid;
        int e = e4 >> 4, d = (e4 & 15) * 4;
        float4 w4 = *(const float4*)(Wfc + e * 64 + d);
        Wfs[d+0][e]=w4.x; Wfs[d+1][e]=w4.y; Wfs[d+2][e]=w4.z; Wfs[d+3][e]=w4.w;
    }
    if (tid < 64) bfs[tid] = bfc[tid];
    float qreg[8];
    #pragma unroll
    for (int r = 0; r < 8; r++)
        qreg[r] = qws[(((size_t)b * TT + rowBase + r) * NH + h) * HD + lane];
    float m[8], lsum[8], acc[8];
    #pragma unroll
    for (int r = 0; r < 8; r++) { m[r] = -INFINITY; lsum[r] = 0.f; acc[r] = 0.f; }
    const float* kbase = keys   + ((size_t)b * TT * NH + h) * HD;
    const float* vbase = values + ((size_t)b * TT * NH + h) * HD;
    for (int kt0 = 0; kt0 < TT; kt0 += 64) {
        __syncthreads();
        #pragma unroll
        for (int rep = 0; rep < 4; rep++) {
            int e4 = rep * 256 + tid;
            int kr = e4 >> 4, d = (e4 & 15) * 4;
            size_t g = ((size_t)(kt0 + kr) * NH) * HD + d;
            float4 k4 = *(const float4*)(kbase + g);
            float4 v4 = *(const float4*)(vbase + g);
            Kt[kr][d+0]=k4.x; Kt[kr][d+1]=k4.y; Kt[kr][d+2]=k4.z; Kt[kr][d+3]=k4.w;
            Vt[kr][d+0]=v4.x; Vt[kr][d+1]=v4.y; Vt[kr][d+2]=v4.z; Vt[kr][d+3]=v4.w;
        }
        __syncthreads();
        float en[8];
        #pragma unroll
        for (int r = 0; r < 8; r++) en[r] = 0.f;
        #pragma unroll 16
        for (int d = 0; d < 64; d++) {
            float kv = Kt[lane][d];
            #pragma unroll
            for (int r = 0; r < 8; r++) en[r] = fmaf(rdlane(qreg[r], d), kv, en[r]);
        }
        const int key = kt0 + lane;
        float p[8], alph[8];
        #pragma unroll
        for (int r = 0; r < 8; r++) {
            float e = en[r];
            if (key == rowBase + r) e = -1e9f;
            e *= 0.125f;
            float tm = e;
            #pragma unroll
            for (int s = 32; s > 0; s >>= 1) tm = fmaxf(tm, __shfl_xor(tm, s, 64));
            float mn = fmaxf(m[r], tm);
            float pvv = __expf(e - mn);
            float ps = pvv;
            #pragma unroll
            for (int s = 32; s > 0; s >>= 1) ps += __shfl_xor(ps, s, 64);
            alph[r] = __expf(m[r] - mn);
            m[r] = mn;
            lsum[r] = lsum[r] * alph[r] + ps;
            p[r] = pvv;
        }
        #pragma unroll
        for (int r = 0; r < 8; r++) acc[r] *= alph[r];
        #pragma unroll 16
        for (int j = 0; j < 64; j++) {
            float vv = Vt[j][lane];
            #pragma unroll
            for (int r = 0; r < 8; r++) acc[r] = fmaf(rdlane(p[r], j), vv, acc[r]);
        }
    }
    #pragma unroll
    for (int r = 0; r < 8; r++) {
        float a = acc[r] / lsum[r];
        float o = bfs[lane];
        #pragma unroll 16
        for (int d = 0; d < 64; d++) o = fmaf(rdlane(a, d), Wfs[d][lane], o);
        out[(((size_t)b * TT + rowBase + r) * NH + h) * HD + lane] = o;
    }
}

// ---------------------------------------------------------------------------
extern "C" void kernel_launch(void* const* d_in, const int* in_sizes, int n_in,
                              void* d_out, int out_size, void* d_ws, size_t ws_size,
                              hipStream_t stream) {
    const float* values  = (const float*)d_in[0];
    const float* keys    = (const float*)d_in[1];
    const float* queries = (const float*)d_in[2];
    const float* Wq      = (const float*)d_in[3];
    const float* Wfc     = (const float*)d_in[4];
    const float* bfc     = (const float*)d_in[5];
    float* out = (float*)d_out;

    const size_t NE = (size_t)BB * TT * EMB;       // 4194304 elems per array
    const size_t need = (6 * NE + 2 * 4096) * sizeof(u16);
    if (ws_size >= need) {
        u16* Qh  = (u16*)d_ws;
        u16* Ql  = Qh + NE;
        u16* Kh  = Qh + 2*NE;
        u16* Kl  = Qh + 3*NE;
        u16* Vth = Qh + 4*NE;
        u16* Vtl = Qh + 5*NE;
        u16* Wh  = Qh + 6*NE;
        u16* Wl  = Wh + 4096;
        qproj_split<<<dim3((BB*TT)/64, EMB/64), 256, 0, stream>>>(queries, Wq, Qh, Ql);
        convert_kv<<<dim3(TT/64, NH, BB), 256, 0, stream>>>(keys, values, Wfc,
                                                            Kh, Kl, Vth, Vtl, Wh, Wl);
        attn_mfma<<<dim3(TT/64, NH, BB), 256, 0, stream>>>(Qh, Ql, Kh, Kl, Vth, Vtl,
                                                           Wh, Wl, bfc, out);
    } else {
        float* qws = (float*)d_ws;
        qproj_f32<<<dim3((BB*TT)/64, EMB/64), 256, 0, stream>>>(queries, Wq, qws);
        attn_valu<<<dim3(TT/32, NH, BB), 256, 0, stream>>>(qws, keys, values, Wfc, bfc, out);
    }
}